// Round 5
// baseline (221.524 us; speedup 1.0000x reference)
//
#include <hip/hip_runtime.h>
#include <math.h>

#define NPTS 2048
#define BLOCK 512
#define NWAVE (BLOCK / 64)

typedef float vfloat4 __attribute__((ext_vector_type(4)));

// One block (512 threads) per batch element. Each thread owns 4 whole points:
// 3 consecutive float4 per tensor (48 B/lane; every 64 B line fully consumed
// across the wave's 3 back-to-back loads). All 6 loads are nontemporal
// (streaming, read-once) and issued in one burst with no loop-carried deps.
// acc: 0-2 sum(p), 3-5 sum(c), 6 sum|p|^2, 7 sum|c|^2, 8-16 sum p_j*c_k.
__global__ __launch_bounds__(BLOCK, 4) void kabsch_kernel(
    const float* __restrict__ P, const float* __restrict__ C,
    float* __restrict__ rmsd_out, int B) {
  const int b = blockIdx.x;
  const int t = threadIdx.x;
  const vfloat4* p4 = (const vfloat4*)(P + (size_t)b * (NPTS * 3));
  const vfloat4* c4 = (const vfloat4*)(C + (size_t)b * (NPTS * 3));

  const int base = 3 * t;  // 512 threads x 3 = 1536 float4 = whole batch
  const vfloat4 pa = __builtin_nontemporal_load(&p4[base]);
  const vfloat4 pb = __builtin_nontemporal_load(&p4[base + 1]);
  const vfloat4 pq = __builtin_nontemporal_load(&p4[base + 2]);
  const vfloat4 ca = __builtin_nontemporal_load(&c4[base]);
  const vfloat4 cb = __builtin_nontemporal_load(&c4[base + 1]);
  const vfloat4 cq = __builtin_nontemporal_load(&c4[base + 2]);

  float acc[17];
#pragma unroll
  for (int i = 0; i < 17; i++) acc[i] = 0.f;

  const float Px[4] = {pa.x, pa.w, pb.z, pq.y};
  const float Py[4] = {pa.y, pb.x, pb.w, pq.z};
  const float Pz[4] = {pa.z, pb.y, pq.x, pq.w};
  const float Cx[4] = {ca.x, ca.w, cb.z, cq.y};
  const float Cy[4] = {ca.y, cb.x, cb.w, cq.z};
  const float Cz[4] = {ca.z, cb.y, cq.x, cq.w};
#pragma unroll
  for (int i = 0; i < 4; i++) {
    const float px = Px[i], py = Py[i], pz = Pz[i];
    const float cx = Cx[i], cy = Cy[i], cz = Cz[i];
    acc[0] += px; acc[1] += py; acc[2] += pz;
    acc[3] += cx; acc[4] += cy; acc[5] += cz;
    acc[6] += px * px + py * py + pz * pz;
    acc[7] += cx * cx + cy * cy + cz * cz;
    acc[8]  += px * cx; acc[9]  += px * cy; acc[10] += px * cz;
    acc[11] += py * cx; acc[12] += py * cy; acc[13] += py * cz;
    acc[14] += pz * cx; acc[15] += pz * cy; acc[16] += pz * cz;
  }

  // wave-level butterfly reduce, then 8-wave combine via LDS
#pragma unroll
  for (int off = 32; off > 0; off >>= 1) {
#pragma unroll
    for (int i = 0; i < 17; i++) acc[i] += __shfl_down(acc[i], off);
  }
  __shared__ float red[NWAVE][17];
  const int wave = t >> 6, lane = t & 63;
  if (lane == 0) {
#pragma unroll
    for (int i = 0; i < 17; i++) red[wave][i] = acc[i];
  }
  __syncthreads();

  if (t == 0) {
    float s[17];
#pragma unroll
    for (int i = 0; i < 17; i++) {
      float v = red[0][i];
#pragma unroll
      for (int w = 1; w < NWAVE; w++) v += red[w][i];
      s[i] = v;
    }
    const float invN = 1.0f / (float)NPTS;
    const float spx = s[0], spy = s[1], spz = s[2];
    const float scx = s[3], scy = s[4], scz = s[5];
    const float Ep = s[6] - (spx * spx + spy * spy + spz * spz) * invN;
    const float Ec = s[7] - (scx * scx + scy * scy + scz * scz) * invN;
    const float a00 = s[8]  - spx * scx * invN, a01 = s[9]  - spx * scy * invN, a02 = s[10] - spx * scz * invN;
    const float a10 = s[11] - spy * scx * invN, a11 = s[12] - spy * scy * invN, a12 = s[13] - spy * scz * invN;
    const float a20 = s[14] - spz * scx * invN, a21 = s[15] - spz * scy * invN, a22 = s[16] - spz * scz * invN;
    const float det = a00 * (a11 * a22 - a12 * a21)
                    - a01 * (a10 * a22 - a12 * a20)
                    + a02 * (a10 * a21 - a11 * a20);
    const float b00 = a00 * a00 + a10 * a10 + a20 * a20;
    const float b11 = a01 * a01 + a11 * a11 + a21 * a21;
    const float b22 = a02 * a02 + a12 * a12 + a22 * a22;
    const float b01 = a00 * a01 + a10 * a11 + a20 * a21;
    const float b02 = a00 * a02 + a10 * a12 + a20 * a22;
    const float b12 = a01 * a02 + a11 * a12 + a21 * a22;
    const float q = (b00 + b11 + b22) * (1.f / 3.f);
    const float p1 = b01 * b01 + b02 * b02 + b12 * b12;
    const float d0 = b00 - q, d1 = b11 - q, d2 = b22 - q;
    const float p2 = d0 * d0 + d1 * d1 + d2 * d2 + 2.f * p1;
    float e1, e2, e3;
    if (p2 < 1e-20f) {
      e1 = e2 = e3 = q;
    } else {
      const float pp = sqrtf(p2 * (1.f / 6.f));
      const float inv = 1.f / pp;
      const float c00 = d0 * inv, c11 = d1 * inv, c22 = d2 * inv;
      const float c01 = b01 * inv, c02 = b02 * inv, c12 = b12 * inv;
      float r = 0.5f * (c00 * (c11 * c22 - c12 * c12)
                      - c01 * (c01 * c22 - c12 * c02)
                      + c02 * (c01 * c12 - c11 * c02));
      r = fminf(1.f, fmaxf(-1.f, r));
      const float phi = acosf(r) * (1.f / 3.f);
      e1 = q + 2.f * pp * cosf(phi);
      e3 = q + 2.f * pp * cosf(phi + 2.0943951023931953f);
      e2 = 3.f * q - e1 - e3;
    }
    const float s1 = sqrtf(fmaxf(e1, 0.f));
    const float s2 = sqrtf(fmaxf(e2, 0.f));
    const float s3 = sqrtf(fmaxf(e3, 0.f));
    const float dsign = (det > 0.f) ? 1.f : ((det < 0.f) ? -1.f : 0.f);
    const float trRS = s1 + s2 + dsign * s3;
    const float msd = (Ep + Ec - 2.f * trRS) * invN;
    rmsd_out[b] = sqrtf(fmaxf(msd, 0.f));
  }
}

// Reduce B per-batch RMSDs -> mean, single block.
__global__ __launch_bounds__(256) void mean_kernel(
    const float* __restrict__ rmsd, float* __restrict__ out, int B) {
  float s = 0.f;
  for (int i = threadIdx.x; i < B; i += 256) s += rmsd[i];
#pragma unroll
  for (int off = 32; off > 0; off >>= 1) s += __shfl_down(s, off);
  __shared__ float sm[4];
  const int wave = threadIdx.x >> 6, lane = threadIdx.x & 63;
  if (lane == 0) sm[wave] = s;
  __syncthreads();
  if (threadIdx.x == 0) {
    float tot = 0.f;
    for (int w = 0; w < 4; w++) tot += sm[w];
    out[0] = tot / (float)B;
  }
}

extern "C" void kernel_launch(void* const* d_in, const int* in_sizes, int n_in,
                              void* d_out, int out_size, void* d_ws, size_t ws_size,
                              hipStream_t stream) {
  const float* P = (const float*)d_in[0];
  const float* C = (const float*)d_in[1];
  float* out = (float*)d_out;
  float* ws = (float*)d_ws;  // B floats of per-batch RMSD
  const int B = in_sizes[0] / (NPTS * 3);
  kabsch_kernel<<<B, BLOCK, 0, stream>>>(P, C, ws, B);
  mean_kernel<<<1, 256, 0, stream>>>(ws, out, B);
}